// Round 1
// baseline (408.156 us; speedup 1.0000x reference)
//
#include <hip/hip_runtime.h>
#include <hip/hip_bf16.h>

// C3 partial connection: 256x6x142x142 fp32 -> 16 branches of 5x5 VALID conv
// over channel subsets -> 256x16x138x138, then 1.7159*tanh(2/3 * y).
//
// Tile: 16 rows x 48 cols per block, 192 threads (16 rows x 12 groups of 4 px).
// LDS-staged input tile (6 ch x 20 x 52 fp32). Channel-major compute with
// constexpr consumer table; weights via uniform scalar loads (SGPR operands).

#define OH 138
#define OW 138
#define IH 142
#define IW 142
#define TH 16
#define TW 48
#define NTHREADS 192

// For each input channel c: the 10 output channels consuming it.
// src: 0=w3 (6,3,5,5), 1=w4 (9,4,5,5), 2=w6 (1,6,5,5). Weight block = src_ptr + idx*25.
struct WEnt { int oc; int src; int idx; };
__device__ constexpr WEnt CH[6][10] = {
  { {0,0,0},{4,0,12},{5,0,15},{6,1,0},{9,1,12},{10,1,16},{11,1,20},{12,1,24},{14,1,32},{15,2,0} },
  { {0,0,1},{1,0,3},{5,0,16},{6,1,1},{7,1,4},{10,1,17},{11,1,21},{12,1,25},{13,1,28},{15,2,1} },
  { {0,0,2},{1,0,4},{2,0,6},{6,1,2},{7,1,5},{8,1,8},{11,1,22},{13,1,29},{14,1,33},{15,2,2} },
  { {1,0,5},{2,0,7},{3,0,9},{6,1,3},{7,1,6},{8,1,9},{9,1,13},{12,1,26},{14,1,34},{15,2,3} },
  { {2,0,8},{3,0,10},{4,0,13},{7,1,7},{8,1,10},{9,1,14},{10,1,18},{12,1,27},{13,1,30},{15,2,4} },
  { {3,0,11},{4,0,14},{5,0,17},{8,1,11},{9,1,15},{10,1,19},{11,1,23},{13,1,31},{14,1,35},{15,2,5} },
};

__global__ __launch_bounds__(NTHREADS, 3)
void c3_kernel(const float* __restrict__ x,
               const float* __restrict__ w3, const float* __restrict__ b3,
               const float* __restrict__ w4, const float* __restrict__ b4,
               const float* __restrict__ w6, const float* __restrict__ b6,
               float* __restrict__ out) {
  __shared__ __attribute__((aligned(16))) float s_in[6][TH + 4][TW + 4];  // 6x20x52 = 24960 B

  const int tid = threadIdx.x;
  const int b   = blockIdx.z;
  // shifted last tiles so every tile is full (overlap writes identical values)
  const int x0 = min((int)blockIdx.x * TW, OW - TW);   // {0,48,90}
  const int y0 = min((int)blockIdx.y * TH, OH - TH);   // {0,16,...,112,122}

  // ---- stage input tile: 6 x 20 x 52 ----
  {
    const size_t img_base = ((size_t)b * 6) * (IH * IW);
    #pragma unroll 4
    for (int i = tid; i < 6 * (TH + 4) * (TW + 4); i += NTHREADS) {
      int c   = i / ((TH + 4) * (TW + 4));
      int rem = i - c * ((TH + 4) * (TW + 4));
      int r   = rem / (TW + 4);
      int col = rem - r * (TW + 4);
      s_in[c][r][col] = x[img_base + (size_t)c * (IH * IW) + (size_t)(y0 + r) * IW + (x0 + col)];
    }
  }
  __syncthreads();

  const int ty  = tid / 12;       // 0..15
  const int gx  = tid - ty * 12;  // 0..11
  const int gx4 = gx * 4;

  // ---- accumulators: 16 oc x 4 px, init to bias ----
  float acc[16][4];
  #pragma unroll
  for (int oc = 0; oc < 16; ++oc) {
    float bv = (oc < 6) ? b3[oc] : (oc < 15) ? b4[oc - 6] : b6[0];
    acc[oc][0] = bv; acc[oc][1] = bv; acc[oc][2] = bv; acc[oc][3] = bv;
  }

  // ---- main compute: channel-major, fully unrolled ----
  #pragma unroll
  for (int c = 0; c < 6; ++c) {
    #pragma unroll
    for (int dy = 0; dy < 5; ++dy) {
      const float* rp = &s_in[c][ty + dy][gx4];
      const float4 a4 = *(const float4*)rp;
      const float4 c4 = *(const float4*)(rp + 4);
      const float win[8] = {a4.x, a4.y, a4.z, a4.w, c4.x, c4.y, c4.z, c4.w};
      #pragma unroll
      for (int j = 0; j < 10; ++j) {
        const int oc  = CH[c][j].oc;
        const int src = CH[c][j].src;
        const float* wp = (src == 0 ? w3 : src == 1 ? w4 : w6) + CH[c][j].idx * 25 + dy * 5;
        #pragma unroll
        for (int dx = 0; dx < 5; ++dx) {
          const float wt = wp[dx];  // wave-uniform -> s_load, SGPR operand
          acc[oc][0] = fmaf(win[dx + 0], wt, acc[oc][0]);
          acc[oc][1] = fmaf(win[dx + 1], wt, acc[oc][1]);
          acc[oc][2] = fmaf(win[dx + 2], wt, acc[oc][2]);
          acc[oc][3] = fmaf(win[dx + 3], wt, acc[oc][3]);
        }
      }
    }
  }

  // ---- epilogue: A*tanh(S*y) and store ----
  const float TS = 1.9235933878519512f;  // 2*S*log2(e), S = 2/3
  const float AOUT = 1.7159f;
  const int oy = y0 + ty;
  const int ox = x0 + gx4;
  #pragma unroll
  for (int oc = 0; oc < 16; ++oc) {
    float r[4];
    #pragma unroll
    for (int p = 0; p < 4; ++p) {
      float t = acc[oc][p] * TS;
      t = fminf(fmaxf(t, -30.f), 30.f);
      const float e = __builtin_amdgcn_exp2f(t);
      r[p] = AOUT * (e - 1.f) * __builtin_amdgcn_rcpf(e + 1.f);
    }
    const size_t off = (((size_t)b * 16 + oc) * OH + oy) * OW + ox;
    *(float2*)&out[off]     = make_float2(r[0], r[1]);  // 8B-aligned: OW even, ox even
    *(float2*)&out[off + 2] = make_float2(r[2], r[3]);
  }
}

extern "C" void kernel_launch(void* const* d_in, const int* in_sizes, int n_in,
                              void* d_out, int out_size, void* d_ws, size_t ws_size,
                              hipStream_t stream) {
  const float* x  = (const float*)d_in[0];
  const float* w3 = (const float*)d_in[1];
  const float* b3 = (const float*)d_in[2];
  const float* w4 = (const float*)d_in[3];
  const float* b4 = (const float*)d_in[4];
  const float* w6 = (const float*)d_in[5];
  const float* b6 = (const float*)d_in[6];
  float* out = (float*)d_out;

  dim3 grid(3, 9, 256);     // x-tiles, y-tiles, batch
  dim3 block(NTHREADS);
  hipLaunchKernelGGL(c3_kernel, grid, block, 0, stream, x, w3, b3, w4, b4, w6, b6, out);
}

// Round 2
// 248.175 us; speedup vs baseline: 1.6446x; 1.6446x over previous
//
#include <hip/hip_runtime.h>
#include <hip/hip_bf16.h>

// C3 partial connection: 256x6x142x142 fp32 -> 16 branches of 5x5 VALID conv
// over channel subsets -> 256x16x138x138, then 1.7159*tanh(2/3 * y).
//
// R2: two passes of 8 output channels; all acc indices / weight offsets are
// compile-time literals (hand-expanded consumer lists). dy loop kept rolled
// (#pragma unroll 1) for I-cache residency. Weights: wave-uniform s_load ->
// SGPR operand in v_fma_f32. 32 fp32 accumulators per pass.

#define OH 138
#define OW 138
#define IH 142
#define IW 142
#define TH 16
#define TW 48
#define NTHREADS 192

__device__ __forceinline__ void load_win(float (&win)[8], const float* __restrict__ rp) {
  const float4 a4 = *(const float4*)rp;
  const float4 c4 = *(const float4*)(rp + 4);
  win[0] = a4.x; win[1] = a4.y; win[2] = a4.z; win[3] = a4.w;
  win[4] = c4.x; win[5] = c4.y; win[6] = c4.z; win[7] = c4.w;
}

// One 5-wide weight row into 4 horizontal output pixels.
__device__ __forceinline__ void tap5(float (&a)[4], const float* __restrict__ wp,
                                     const float (&win)[8]) {
  #pragma unroll
  for (int dx = 0; dx < 5; ++dx) {
    const float wt = wp[dx];  // wave-uniform -> s_load, SGPR operand
    a[0] = fmaf(win[dx + 0], wt, a[0]);
    a[1] = fmaf(win[dx + 1], wt, a[1]);
    a[2] = fmaf(win[dx + 2], wt, a[2]);
    a[3] = fmaf(win[dx + 3], wt, a[3]);
  }
}

__device__ __forceinline__ float act(float y) {
  const float TS = 1.9235933878519512f;  // 2*(2/3)*log2(e)
  float t = y * TS;
  t = fminf(fmaxf(t, -30.f), 30.f);
  const float e = __builtin_amdgcn_exp2f(t);
  return 1.7159f * (e - 1.f) * __builtin_amdgcn_rcpf(e + 1.f);
}

__global__ __launch_bounds__(NTHREADS, 4)
void c3_kernel(const float* __restrict__ x,
               const float* __restrict__ w3, const float* __restrict__ b3,
               const float* __restrict__ w4, const float* __restrict__ b4,
               const float* __restrict__ w6, const float* __restrict__ b6,
               float* __restrict__ out) {
  __shared__ __attribute__((aligned(16))) float s_in[6][TH + 4][TW + 4];  // 6x20x52

  const int tid = threadIdx.x;
  const int b   = blockIdx.z;
  const int x0 = min((int)blockIdx.x * TW, OW - TW);   // {0,48,90}
  const int y0 = min((int)blockIdx.y * TH, OH - TH);   // {0,16,...,112,122}

  // ---- stage input tile: 6 x 20 x 52 ----
  {
    const size_t img_base = ((size_t)b * 6) * (IH * IW);
    #pragma unroll 4
    for (int i = tid; i < 6 * (TH + 4) * (TW + 4); i += NTHREADS) {
      int c   = i / ((TH + 4) * (TW + 4));
      int rem = i - c * ((TH + 4) * (TW + 4));
      int r   = rem / (TW + 4);
      int col = rem - r * (TW + 4);
      s_in[c][r][col] = x[img_base + (size_t)c * (IH * IW) + (size_t)(y0 + r) * IW + (x0 + col)];
    }
  }
  __syncthreads();

  const int ty  = tid / 12;       // 0..15
  const int gx  = tid - ty * 12;  // 0..11
  const int gx4 = gx * 4;
  const int oy = y0 + ty;
  const int ox = x0 + gx4;
  const size_t out_img = (size_t)b * 16;

  // ================= pass 0: oc 0..7 =================
  {
    float acc[8][4];
    #pragma unroll
    for (int k = 0; k < 8; ++k) {
      const float bv = (k < 6) ? b3[k] : b4[k - 6];
      acc[k][0] = bv; acc[k][1] = bv; acc[k][2] = bv; acc[k][3] = bv;
    }

    #pragma unroll 1
    for (int dy = 0; dy < 5; ++dy) {
      const int ry = ty + dy;
      const float* __restrict__ w3d = w3 + dy * 5;
      const float* __restrict__ w4d = w4 + dy * 5;
      // c0: oc0(w3:0) oc4(w3:12) oc5(w3:15) oc6(w4:0)
      { float win[8]; load_win(win, &s_in[0][ry][gx4]);
        tap5(acc[0], w3d +  0 * 25, win);
        tap5(acc[4], w3d + 12 * 25, win);
        tap5(acc[5], w3d + 15 * 25, win);
        tap5(acc[6], w4d +  0 * 25, win); }
      // c1: oc0(w3:1) oc1(w3:3) oc5(w3:16) oc6(w4:1) oc7(w4:4)
      { float win[8]; load_win(win, &s_in[1][ry][gx4]);
        tap5(acc[0], w3d +  1 * 25, win);
        tap5(acc[1], w3d +  3 * 25, win);
        tap5(acc[5], w3d + 16 * 25, win);
        tap5(acc[6], w4d +  1 * 25, win);
        tap5(acc[7], w4d +  4 * 25, win); }
      // c2: oc0(w3:2) oc1(w3:4) oc2(w3:6) oc6(w4:2) oc7(w4:5)
      { float win[8]; load_win(win, &s_in[2][ry][gx4]);
        tap5(acc[0], w3d +  2 * 25, win);
        tap5(acc[1], w3d +  4 * 25, win);
        tap5(acc[2], w3d +  6 * 25, win);
        tap5(acc[6], w4d +  2 * 25, win);
        tap5(acc[7], w4d +  5 * 25, win); }
      // c3: oc1(w3:5) oc2(w3:7) oc3(w3:9) oc6(w4:3) oc7(w4:6)
      { float win[8]; load_win(win, &s_in[3][ry][gx4]);
        tap5(acc[1], w3d +  5 * 25, win);
        tap5(acc[2], w3d +  7 * 25, win);
        tap5(acc[3], w3d +  9 * 25, win);
        tap5(acc[6], w4d +  3 * 25, win);
        tap5(acc[7], w4d +  6 * 25, win); }
      // c4: oc2(w3:8) oc3(w3:10) oc4(w3:13) oc7(w4:7)
      { float win[8]; load_win(win, &s_in[4][ry][gx4]);
        tap5(acc[2], w3d +  8 * 25, win);
        tap5(acc[3], w3d + 10 * 25, win);
        tap5(acc[4], w3d + 13 * 25, win);
        tap5(acc[7], w4d +  7 * 25, win); }
      // c5: oc3(w3:11) oc4(w3:14) oc5(w3:17)
      { float win[8]; load_win(win, &s_in[5][ry][gx4]);
        tap5(acc[3], w3d + 11 * 25, win);
        tap5(acc[4], w3d + 14 * 25, win);
        tap5(acc[5], w3d + 17 * 25, win); }
    }

    #pragma unroll
    for (int k = 0; k < 8; ++k) {
      const size_t off = ((out_img + k) * OH + oy) * OW + ox;
      *(float2*)&out[off]     = make_float2(act(acc[k][0]), act(acc[k][1]));
      *(float2*)&out[off + 2] = make_float2(act(acc[k][2]), act(acc[k][3]));
    }
  }

  // ================= pass 1: oc 8..15 =================
  {
    float acc[8][4];
    #pragma unroll
    for (int k = 0; k < 8; ++k) {
      const float bv = (k < 7) ? b4[k + 2] : b6[0];
      acc[k][0] = bv; acc[k][1] = bv; acc[k][2] = bv; acc[k][3] = bv;
    }

    #pragma unroll 1
    for (int dy = 0; dy < 5; ++dy) {
      const int ry = ty + dy;
      const float* __restrict__ w4d = w4 + dy * 5;
      const float* __restrict__ w6d = w6 + dy * 5;
      // acc idx = oc-8. c0: oc9(w4:12) oc10(w4:16) oc11(w4:20) oc12(w4:24) oc14(w4:32) oc15(w6:0)
      { float win[8]; load_win(win, &s_in[0][ry][gx4]);
        tap5(acc[1], w4d + 12 * 25, win);
        tap5(acc[2], w4d + 16 * 25, win);
        tap5(acc[3], w4d + 20 * 25, win);
        tap5(acc[4], w4d + 24 * 25, win);
        tap5(acc[6], w4d + 32 * 25, win);
        tap5(acc[7], w6d +  0 * 25, win); }
      // c1: oc10(w4:17) oc11(w4:21) oc12(w4:25) oc13(w4:28) oc15(w6:1)
      { float win[8]; load_win(win, &s_in[1][ry][gx4]);
        tap5(acc[2], w4d + 17 * 25, win);
        tap5(acc[3], w4d + 21 * 25, win);
        tap5(acc[4], w4d + 25 * 25, win);
        tap5(acc[5], w4d + 28 * 25, win);
        tap5(acc[7], w6d +  1 * 25, win); }
      // c2: oc8(w4:8) oc11(w4:22) oc13(w4:29) oc14(w4:33) oc15(w6:2)
      { float win[8]; load_win(win, &s_in[2][ry][gx4]);
        tap5(acc[0], w4d +  8 * 25, win);
        tap5(acc[3], w4d + 22 * 25, win);
        tap5(acc[5], w4d + 29 * 25, win);
        tap5(acc[6], w4d + 33 * 25, win);
        tap5(acc[7], w6d +  2 * 25, win); }
      // c3: oc8(w4:9) oc9(w4:13) oc12(w4:26) oc14(w4:34) oc15(w6:3)
      { float win[8]; load_win(win, &s_in[3][ry][gx4]);
        tap5(acc[0], w4d +  9 * 25, win);
        tap5(acc[1], w4d + 13 * 25, win);
        tap5(acc[4], w4d + 26 * 25, win);
        tap5(acc[6], w4d + 34 * 25, win);
        tap5(acc[7], w6d +  3 * 25, win); }
      // c4: oc8(w4:10) oc9(w4:14) oc10(w4:18) oc12(w4:27) oc13(w4:30) oc15(w6:4)
      { float win[8]; load_win(win, &s_in[4][ry][gx4]);
        tap5(acc[0], w4d + 10 * 25, win);
        tap5(acc[1], w4d + 14 * 25, win);
        tap5(acc[2], w4d + 18 * 25, win);
        tap5(acc[4], w4d + 27 * 25, win);
        tap5(acc[5], w4d + 30 * 25, win);
        tap5(acc[7], w6d +  4 * 25, win); }
      // c5: oc8(w4:11) oc9(w4:15) oc10(w4:19) oc11(w4:23) oc13(w4:31) oc14(w4:35) oc15(w6:5)
      { float win[8]; load_win(win, &s_in[5][ry][gx4]);
        tap5(acc[0], w4d + 11 * 25, win);
        tap5(acc[1], w4d + 15 * 25, win);
        tap5(acc[2], w4d + 19 * 25, win);
        tap5(acc[3], w4d + 23 * 25, win);
        tap5(acc[5], w4d + 31 * 25, win);
        tap5(acc[6], w4d + 35 * 25, win);
        tap5(acc[7], w6d +  5 * 25, win); }
    }

    #pragma unroll
    for (int k = 0; k < 8; ++k) {
      const size_t off = ((out_img + 8 + k) * OH + oy) * OW + ox;
      *(float2*)&out[off]     = make_float2(act(acc[k][0]), act(acc[k][1]));
      *(float2*)&out[off + 2] = make_float2(act(acc[k][2]), act(acc[k][3]));
    }
  }
}

extern "C" void kernel_launch(void* const* d_in, const int* in_sizes, int n_in,
                              void* d_out, int out_size, void* d_ws, size_t ws_size,
                              hipStream_t stream) {
  const float* x  = (const float*)d_in[0];
  const float* w3 = (const float*)d_in[1];
  const float* b3 = (const float*)d_in[2];
  const float* w4 = (const float*)d_in[3];
  const float* b4 = (const float*)d_in[4];
  const float* w6 = (const float*)d_in[5];
  const float* b6 = (const float*)d_in[6];
  float* out = (float*)d_out;

  dim3 grid(3, 9, 256);     // x-tiles, y-tiles, batch
  dim3 block(NTHREADS);
  hipLaunchKernelGGL(c3_kernel, grid, block, 0, stream, x, w3, b3, w4, b4, w6, b6, out);
}

// Round 3
// 232.770 us; speedup vs baseline: 1.7535x; 1.0662x over previous
//
#include <hip/hip_runtime.h>
#include <hip/hip_bf16.h>

// C3 partial connection: 256x6x142x142 fp32 -> 16 branches of 5x5 VALID conv
// over channel subsets -> 256x16x138x138, then 1.7159*tanh(2/3 * y).
//
// R3: SINGLE pass over all 16 output channels (64 static accumulators).
// Per dy: 6 channel windows loaded in 2 register-scoped groups of 3,
// then 60 fully-literal tap5 calls (1200 FMAs). Halves LDS reads vs R2.
// Weights: wave-uniform s_load -> SGPR operand in v_fma_f32.

#define OH 138
#define OW 138
#define IH 142
#define IW 142
#define TH 16
#define TW 48
#define NTHREADS 192

__device__ __forceinline__ void load_win(float (&win)[8], const float* __restrict__ rp) {
  const float4 a4 = *(const float4*)rp;
  const float4 c4 = *(const float4*)(rp + 4);
  win[0] = a4.x; win[1] = a4.y; win[2] = a4.z; win[3] = a4.w;
  win[4] = c4.x; win[5] = c4.y; win[6] = c4.z; win[7] = c4.w;
}

// One 5-wide weight row into 4 horizontal output pixels.
__device__ __forceinline__ void tap5(float (&a)[4], const float* __restrict__ wp,
                                     const float (&win)[8]) {
  #pragma unroll
  for (int dx = 0; dx < 5; ++dx) {
    const float wt = wp[dx];  // wave-uniform -> s_load, SGPR operand
    a[0] = fmaf(win[dx + 0], wt, a[0]);
    a[1] = fmaf(win[dx + 1], wt, a[1]);
    a[2] = fmaf(win[dx + 2], wt, a[2]);
    a[3] = fmaf(win[dx + 3], wt, a[3]);
  }
}

__device__ __forceinline__ float act(float y) {
  const float TS = 1.9235933878519512f;  // 2*(2/3)*log2(e)
  float t = y * TS;
  t = fminf(fmaxf(t, -30.f), 30.f);
  const float e = __builtin_amdgcn_exp2f(t);
  return 1.7159f * (e - 1.f) * __builtin_amdgcn_rcpf(e + 1.f);
}

__global__ __launch_bounds__(NTHREADS, 4)
void c3_kernel(const float* __restrict__ x,
               const float* __restrict__ w3, const float* __restrict__ b3,
               const float* __restrict__ w4, const float* __restrict__ b4,
               const float* __restrict__ w6, const float* __restrict__ b6,
               float* __restrict__ out) {
  __shared__ __attribute__((aligned(16))) float s_in[6][TH + 4][TW + 4];  // 6x20x52

  const int tid = threadIdx.x;
  const int b   = blockIdx.z;
  const int x0 = min((int)blockIdx.x * TW, OW - TW);   // {0,48,90}
  const int y0 = min((int)blockIdx.y * TH, OH - TH);   // {0,16,...,112,122}

  // ---- stage input tile: 6 x 20 x 52 ----
  {
    const size_t img_base = ((size_t)b * 6) * (IH * IW);
    #pragma unroll 4
    for (int i = tid; i < 6 * (TH + 4) * (TW + 4); i += NTHREADS) {
      int c   = i / ((TH + 4) * (TW + 4));
      int rem = i - c * ((TH + 4) * (TW + 4));
      int r   = rem / (TW + 4);
      int col = rem - r * (TW + 4);
      s_in[c][r][col] = x[img_base + (size_t)c * (IH * IW) + (size_t)(y0 + r) * IW + (x0 + col)];
    }
  }
  __syncthreads();

  const int ty  = tid / 12;       // 0..15
  const int gx  = tid - ty * 12;  // 0..11
  const int gx4 = gx * 4;
  const int oy = y0 + ty;
  const int ox = x0 + gx4;

  // ---- 16 oc x 4 px static accumulators, init to bias ----
  float acc[16][4];
  #pragma unroll
  for (int k = 0; k < 16; ++k) {
    const float bv = (k < 6) ? b3[k] : (k < 15) ? b4[k - 6] : b6[0];
    acc[k][0] = bv; acc[k][1] = bv; acc[k][2] = bv; acc[k][3] = bv;
  }

  #pragma unroll 1
  for (int dy = 0; dy < 5; ++dy) {
    const int ry = ty + dy;
    const float* __restrict__ w3d = w3 + dy * 5;
    const float* __restrict__ w4d = w4 + dy * 5;
    const float* __restrict__ w6d = w6 + dy * 5;

    // ---- channel group 0..2 ----
    {
      float win0[8], win1[8], win2[8];
      load_win(win0, &s_in[0][ry][gx4]);
      load_win(win1, &s_in[1][ry][gx4]);
      load_win(win2, &s_in[2][ry][gx4]);
      // c0: oc0 oc4 oc5 oc6 oc9 oc10 oc11 oc12 oc14 oc15
      tap5(acc[ 0], w3d +  0 * 25, win0);
      tap5(acc[ 4], w3d + 12 * 25, win0);
      tap5(acc[ 5], w3d + 15 * 25, win0);
      tap5(acc[ 6], w4d +  0 * 25, win0);
      tap5(acc[ 9], w4d + 12 * 25, win0);
      tap5(acc[10], w4d + 16 * 25, win0);
      tap5(acc[11], w4d + 20 * 25, win0);
      tap5(acc[12], w4d + 24 * 25, win0);
      tap5(acc[14], w4d + 32 * 25, win0);
      tap5(acc[15], w6d +  0 * 25, win0);
      // c1: oc0 oc1 oc5 oc6 oc7 oc10 oc11 oc12 oc13 oc15
      tap5(acc[ 0], w3d +  1 * 25, win1);
      tap5(acc[ 1], w3d +  3 * 25, win1);
      tap5(acc[ 5], w3d + 16 * 25, win1);
      tap5(acc[ 6], w4d +  1 * 25, win1);
      tap5(acc[ 7], w4d +  4 * 25, win1);
      tap5(acc[10], w4d + 17 * 25, win1);
      tap5(acc[11], w4d + 21 * 25, win1);
      tap5(acc[12], w4d + 25 * 25, win1);
      tap5(acc[13], w4d + 28 * 25, win1);
      tap5(acc[15], w6d +  1 * 25, win1);
      // c2: oc0 oc1 oc2 oc6 oc7 oc8 oc11 oc13 oc14 oc15
      tap5(acc[ 0], w3d +  2 * 25, win2);
      tap5(acc[ 1], w3d +  4 * 25, win2);
      tap5(acc[ 2], w3d +  6 * 25, win2);
      tap5(acc[ 6], w4d +  2 * 25, win2);
      tap5(acc[ 7], w4d +  5 * 25, win2);
      tap5(acc[ 8], w4d +  8 * 25, win2);
      tap5(acc[11], w4d + 22 * 25, win2);
      tap5(acc[13], w4d + 29 * 25, win2);
      tap5(acc[14], w4d + 33 * 25, win2);
      tap5(acc[15], w6d +  2 * 25, win2);
    }
    // ---- channel group 3..5 ----
    {
      float win3[8], win4[8], win5[8];
      load_win(win3, &s_in[3][ry][gx4]);
      load_win(win4, &s_in[4][ry][gx4]);
      load_win(win5, &s_in[5][ry][gx4]);
      // c3: oc1 oc2 oc3 oc6 oc7 oc8 oc9 oc12 oc14 oc15
      tap5(acc[ 1], w3d +  5 * 25, win3);
      tap5(acc[ 2], w3d +  7 * 25, win3);
      tap5(acc[ 3], w3d +  9 * 25, win3);
      tap5(acc[ 6], w4d +  3 * 25, win3);
      tap5(acc[ 7], w4d +  6 * 25, win3);
      tap5(acc[ 8], w4d +  9 * 25, win3);
      tap5(acc[ 9], w4d + 13 * 25, win3);
      tap5(acc[12], w4d + 26 * 25, win3);
      tap5(acc[14], w4d + 34 * 25, win3);
      tap5(acc[15], w6d +  3 * 25, win3);
      // c4: oc2 oc3 oc4 oc7 oc8 oc9 oc10 oc12 oc13 oc15
      tap5(acc[ 2], w3d +  8 * 25, win4);
      tap5(acc[ 3], w3d + 10 * 25, win4);
      tap5(acc[ 4], w3d + 13 * 25, win4);
      tap5(acc[ 7], w4d +  7 * 25, win4);
      tap5(acc[ 8], w4d + 10 * 25, win4);
      tap5(acc[ 9], w4d + 14 * 25, win4);
      tap5(acc[10], w4d + 18 * 25, win4);
      tap5(acc[12], w4d + 27 * 25, win4);
      tap5(acc[13], w4d + 30 * 25, win4);
      tap5(acc[15], w6d +  4 * 25, win4);
      // c5: oc3 oc4 oc5 oc8 oc9 oc10 oc11 oc13 oc14 oc15
      tap5(acc[ 3], w3d + 11 * 25, win5);
      tap5(acc[ 4], w3d + 14 * 25, win5);
      tap5(acc[ 5], w3d + 17 * 25, win5);
      tap5(acc[ 8], w4d + 11 * 25, win5);
      tap5(acc[ 9], w4d + 15 * 25, win5);
      tap5(acc[10], w4d + 19 * 25, win5);
      tap5(acc[11], w4d + 23 * 25, win5);
      tap5(acc[13], w4d + 31 * 25, win5);
      tap5(acc[14], w4d + 35 * 25, win5);
      tap5(acc[15], w6d +  5 * 25, win5);
    }
  }

  // ---- epilogue: A*tanh(S*y) and store ----
  const size_t out_img = (size_t)b * 16;
  #pragma unroll
  for (int k = 0; k < 16; ++k) {
    const size_t off = ((out_img + k) * OH + oy) * OW + ox;
    *(float2*)&out[off]     = make_float2(act(acc[k][0]), act(acc[k][1]));
    *(float2*)&out[off + 2] = make_float2(act(acc[k][2]), act(acc[k][3]));
  }
}

extern "C" void kernel_launch(void* const* d_in, const int* in_sizes, int n_in,
                              void* d_out, int out_size, void* d_ws, size_t ws_size,
                              hipStream_t stream) {
  const float* x  = (const float*)d_in[0];
  const float* w3 = (const float*)d_in[1];
  const float* b3 = (const float*)d_in[2];
  const float* w4 = (const float*)d_in[3];
  const float* b4 = (const float*)d_in[4];
  const float* w6 = (const float*)d_in[5];
  const float* b6 = (const float*)d_in[6];
  float* out = (float*)d_out;

  dim3 grid(3, 9, 256);     // x-tiles, y-tiles, batch
  dim3 block(NTHREADS);
  hipLaunchKernelGGL(c3_kernel, grid, block, 0, stream, x, w3, b3, w4, b4, w6, b6, out);
}

// Round 4
// 212.293 us; speedup vs baseline: 1.9226x; 1.0965x over previous
//
#include <hip/hip_runtime.h>
#include <hip/hip_bf16.h>

// C3 partial connection: 256x6x142x142 fp32 -> 16 branches of 5x5 VALID conv
// over channel subsets -> 256x16x138x138, then 1.7159*tanh(2/3 * y).
//
// R4: v_dot2_f32_f16 (2 MAC/instr, fp32 accumulate). Inputs converted to f16
// in LDS as two phase-shifted half2 arrays (even pairs / odd pairs) so each
// pixel window is 4 aligned dwords. Weights pre-packed to half2 by a prep
// kernel into d_ws (900 dwords), consumed as wave-uniform s_load SGPRs.
// 15 dot2 per 5x5 tap-block instead of 25 FMA -> 3600 VALU MAC-instr/thread.

#define OH 138
#define OW 138
#define IH 142
#define IW 142
#define TH 16
#define TW 48
#define NTHREADS 192

typedef _Float16 h2 __attribute__((ext_vector_type(2)));

// slot -> (src, idx): src 0=w3(6,3,5,5) 1=w4(9,4,5,5) 2=w6(1,6,5,5); block = idx*25
__device__ __constant__ const int WS[60][2] = {
  // c0 slots 0-9  (oc: 0,4,5,6,9,10,11,12,14,15)
  {0,0},{0,12},{0,15},{1,0},{1,12},{1,16},{1,20},{1,24},{1,32},{2,0},
  // c1 slots 10-19 (oc: 0,1,5,6,7,10,11,12,13,15)
  {0,1},{0,3},{0,16},{1,1},{1,4},{1,17},{1,21},{1,25},{1,28},{2,1},
  // c2 slots 20-29 (oc: 0,1,2,6,7,8,11,13,14,15)
  {0,2},{0,4},{0,6},{1,2},{1,5},{1,8},{1,22},{1,29},{1,33},{2,2},
  // c3 slots 30-39 (oc: 1,2,3,6,7,8,9,12,14,15)
  {0,5},{0,7},{0,9},{1,3},{1,6},{1,9},{1,13},{1,26},{1,34},{2,3},
  // c4 slots 40-49 (oc: 2,3,4,7,8,9,10,12,13,15)
  {0,8},{0,10},{0,13},{1,7},{1,10},{1,14},{1,18},{1,27},{1,30},{2,4},
  // c5 slots 50-59 (oc: 3,4,5,8,9,10,11,13,14,15)
  {0,11},{0,14},{0,17},{1,11},{1,15},{1,19},{1,23},{1,31},{1,35},{2,5},
};

// ---- prep kernel: pack weights to half2 table in d_ws (900 dwords) ----
// tab[(slot*5 + dy)*3 + j] = half2(w[2j], j<2 ? w[2j+1] : 0)
__global__ void wpack_kernel(const float* __restrict__ w3, const float* __restrict__ w4,
                             const float* __restrict__ w6, unsigned int* __restrict__ tab) {
  int t = blockIdx.x * 256 + threadIdx.x;
  if (t >= 900) return;
  int slot = t / 15, rem = t - slot * 15;
  int dy = rem / 3, j = rem - dy * 3;
  int src = WS[slot][0], idx = WS[slot][1];
  const float* bp = (src == 0 ? w3 : src == 1 ? w4 : w6) + idx * 25 + dy * 5 + 2 * j;
  float a = bp[0];
  float b = (j < 2) ? bp[1] : 0.f;
  h2 p; p.x = (_Float16)a; p.y = (_Float16)b;   // RTN converts
  tab[t] = __builtin_bit_cast(unsigned int, p);
}

__device__ __forceinline__ unsigned int pk(float a, float b) {
  h2 p; p.x = (_Float16)a; p.y = (_Float16)b;
  return __builtin_bit_cast(unsigned int, p);
}

__device__ __forceinline__ float fd2(unsigned int xu, unsigned int wu, float c) {
#if __has_builtin(__builtin_amdgcn_fdot2)
  return __builtin_amdgcn_fdot2(__builtin_bit_cast(h2, xu), __builtin_bit_cast(h2, wu), c, false);
#else
  h2 a = __builtin_bit_cast(h2, xu), b = __builtin_bit_cast(h2, wu);
  return c + (float)a.x * (float)b.x + (float)a.y * (float)b.y;
#endif
}

// 12 dot2: one 5-tap weight row into 4 horizontal output pixels.
// E[k] = (x[P+2k], x[P+2k+1]); O[k] = (x[P+2k+1], x[P+2k+2]); P = pixel-group base.
__device__ __forceinline__ void slot_taps(float (&a)[4], const unsigned int* __restrict__ tp,
                                          const unsigned int (&E)[4], const unsigned int (&O)[4]) {
  const unsigned int w01 = tp[0], w23 = tp[1], w4z = tp[2];  // wave-uniform -> SGPR
  a[0] = fd2(E[0], w01, a[0]); a[0] = fd2(E[1], w23, a[0]); a[0] = fd2(E[2], w4z, a[0]);
  a[1] = fd2(O[0], w01, a[1]); a[1] = fd2(O[1], w23, a[1]); a[1] = fd2(O[2], w4z, a[1]);
  a[2] = fd2(E[1], w01, a[2]); a[2] = fd2(E[2], w23, a[2]); a[2] = fd2(E[3], w4z, a[2]);
  a[3] = fd2(O[1], w01, a[3]); a[3] = fd2(O[2], w23, a[3]); a[3] = fd2(O[3], w4z, a[3]);
}

__device__ __forceinline__ void ldwin(unsigned int (&E)[4], unsigned int (&O)[4],
                                      const unsigned int* __restrict__ se_r,
                                      const unsigned int* __restrict__ so_r, int k) {
  *(uint2*)&E[0] = *(const uint2*)(se_r + k);
  *(uint2*)&E[2] = *(const uint2*)(se_r + k + 2);
  *(uint2*)&O[0] = *(const uint2*)(so_r + k);
  *(uint2*)&O[2] = *(const uint2*)(so_r + k + 2);
}

__device__ __forceinline__ float act(float y) {
  const float TS = 1.9235933878519512f;  // 2*(2/3)*log2(e)
  const float e = __builtin_amdgcn_exp2f(y * TS);
  // A*tanh(S*y) = A - 2A/(exp2(TS*y)+1); exp2->inf gives rcp->0 (A), exp2->0 gives -A.
  return fmaf(-2.f * 1.7159f, __builtin_amdgcn_rcpf(e + 1.f), 1.7159f);
}

__global__ __launch_bounds__(NTHREADS, 4)
void c3_kernel(const float* __restrict__ x,
               const float* __restrict__ b3, const float* __restrict__ b4,
               const float* __restrict__ b6, const unsigned int* __restrict__ tab,
               float* __restrict__ out) {
  // even pairs / odd pairs, 6 ch x 20 rows x 26 half2 each = 24960 B total
  __shared__ __attribute__((aligned(16))) unsigned int se[6][TH + 4][26];
  __shared__ __attribute__((aligned(16))) unsigned int so[6][TH + 4][26];

  const int tid = threadIdx.x;
  const int b   = blockIdx.z;
  const int x0 = min((int)blockIdx.x * TW, OW - TW);   // {0,48,90}
  const int y0 = min((int)blockIdx.y * TH, OH - TH);   // {0,16,...,112,122}

  // ---- stage + convert: 6 x 20 rows x 13 quads of fp32 -> half2 pairs ----
  {
    const size_t img_base = (size_t)b * 6 * (IH * IW);
    for (int i = tid; i < 6 * (TH + 4) * 13; i += NTHREADS) {
      int c   = i / ((TH + 4) * 13);
      int rem = i - c * ((TH + 4) * 13);
      int r   = rem / 13;
      int q   = rem - r * 13;
      const float* rowp = x + img_base + (size_t)c * (IH * IW) + (size_t)(y0 + r) * IW + x0;
      const float4 v = *(const float4*)(rowp + 4 * q);
      const float xn = rowp[min(4 * q + 4, 51)];  // clamp: q=12's pad elem (never used w/ real weight)
      se[c][r][2 * q]     = pk(v.x, v.y);
      se[c][r][2 * q + 1] = pk(v.z, v.w);
      so[c][r][2 * q]     = pk(v.y, v.z);
      so[c][r][2 * q + 1] = pk(v.w, xn);
    }
  }
  __syncthreads();

  const int ty  = tid / 12;       // 0..15
  const int gx  = tid - ty * 12;  // 0..11
  const int k2  = 2 * gx;
  const int oy = y0 + ty;
  const int ox = x0 + gx * 4;

  // ---- 16 oc x 4 px accumulators, init to bias ----
  float acc[16][4];
  #pragma unroll
  for (int k = 0; k < 16; ++k) {
    const float bv = (k < 6) ? b3[k] : (k < 15) ? b4[k - 6] : b6[0];
    acc[k][0] = bv; acc[k][1] = bv; acc[k][2] = bv; acc[k][3] = bv;
  }

  #pragma unroll 1
  for (int dy = 0; dy < 5; ++dy) {
    const int ry = ty + dy;
    const unsigned int* __restrict__ td = tab + dy * 3;

    // ---- channels 0..2 ----
    {
      unsigned int E0[4], O0[4], E1[4], O1[4], E2[4], O2[4];
      ldwin(E0, O0, &se[0][ry][0], &so[0][ry][0], k2);
      ldwin(E1, O1, &se[1][ry][0], &so[1][ry][0], k2);
      ldwin(E2, O2, &se[2][ry][0], &so[2][ry][0], k2);
      // c0: slots 0-9
      slot_taps(acc[ 0], td +  0 * 15, E0, O0);
      slot_taps(acc[ 4], td +  1 * 15, E0, O0);
      slot_taps(acc[ 5], td +  2 * 15, E0, O0);
      slot_taps(acc[ 6], td +  3 * 15, E0, O0);
      slot_taps(acc[ 9], td +  4 * 15, E0, O0);
      slot_taps(acc[10], td +  5 * 15, E0, O0);
      slot_taps(acc[11], td +  6 * 15, E0, O0);
      slot_taps(acc[12], td +  7 * 15, E0, O0);
      slot_taps(acc[14], td +  8 * 15, E0, O0);
      slot_taps(acc[15], td +  9 * 15, E0, O0);
      // c1: slots 10-19
      slot_taps(acc[ 0], td + 10 * 15, E1, O1);
      slot_taps(acc[ 1], td + 11 * 15, E1, O1);
      slot_taps(acc[ 5], td + 12 * 15, E1, O1);
      slot_taps(acc[ 6], td + 13 * 15, E1, O1);
      slot_taps(acc[ 7], td + 14 * 15, E1, O1);
      slot_taps(acc[10], td + 15 * 15, E1, O1);
      slot_taps(acc[11], td + 16 * 15, E1, O1);
      slot_taps(acc[12], td + 17 * 15, E1, O1);
      slot_taps(acc[13], td + 18 * 15, E1, O1);
      slot_taps(acc[15], td + 19 * 15, E1, O1);
      // c2: slots 20-29
      slot_taps(acc[ 0], td + 20 * 15, E2, O2);
      slot_taps(acc[ 1], td + 21 * 15, E2, O2);
      slot_taps(acc[ 2], td + 22 * 15, E2, O2);
      slot_taps(acc[ 6], td + 23 * 15, E2, O2);
      slot_taps(acc[ 7], td + 24 * 15, E2, O2);
      slot_taps(acc[ 8], td + 25 * 15, E2, O2);
      slot_taps(acc[11], td + 26 * 15, E2, O2);
      slot_taps(acc[13], td + 27 * 15, E2, O2);
      slot_taps(acc[14], td + 28 * 15, E2, O2);
      slot_taps(acc[15], td + 29 * 15, E2, O2);
    }
    // ---- channels 3..5 ----
    {
      unsigned int E3[4], O3[4], E4[4], O4[4], E5[4], O5[4];
      ldwin(E3, O3, &se[3][ry][0], &so[3][ry][0], k2);
      ldwin(E4, O4, &se[4][ry][0], &so[4][ry][0], k2);
      ldwin(E5, O5, &se[5][ry][0], &so[5][ry][0], k2);
      // c3: slots 30-39
      slot_taps(acc[ 1], td + 30 * 15, E3, O3);
      slot_taps(acc[ 2], td + 31 * 15, E3, O3);
      slot_taps(acc[ 3], td + 32 * 15, E3, O3);
      slot_taps(acc[ 6], td + 33 * 15, E3, O3);
      slot_taps(acc[ 7], td + 34 * 15, E3, O3);
      slot_taps(acc[ 8], td + 35 * 15, E3, O3);
      slot_taps(acc[ 9], td + 36 * 15, E3, O3);
      slot_taps(acc[12], td + 37 * 15, E3, O3);
      slot_taps(acc[14], td + 38 * 15, E3, O3);
      slot_taps(acc[15], td + 39 * 15, E3, O3);
      // c4: slots 40-49
      slot_taps(acc[ 2], td + 40 * 15, E4, O4);
      slot_taps(acc[ 3], td + 41 * 15, E4, O4);
      slot_taps(acc[ 4], td + 42 * 15, E4, O4);
      slot_taps(acc[ 7], td + 43 * 15, E4, O4);
      slot_taps(acc[ 8], td + 44 * 15, E4, O4);
      slot_taps(acc[ 9], td + 45 * 15, E4, O4);
      slot_taps(acc[10], td + 46 * 15, E4, O4);
      slot_taps(acc[12], td + 47 * 15, E4, O4);
      slot_taps(acc[13], td + 48 * 15, E4, O4);
      slot_taps(acc[15], td + 49 * 15, E4, O4);
      // c5: slots 50-59
      slot_taps(acc[ 3], td + 50 * 15, E5, O5);
      slot_taps(acc[ 4], td + 51 * 15, E5, O5);
      slot_taps(acc[ 5], td + 52 * 15, E5, O5);
      slot_taps(acc[ 8], td + 53 * 15, E5, O5);
      slot_taps(acc[ 9], td + 54 * 15, E5, O5);
      slot_taps(acc[10], td + 55 * 15, E5, O5);
      slot_taps(acc[11], td + 56 * 15, E5, O5);
      slot_taps(acc[13], td + 57 * 15, E5, O5);
      slot_taps(acc[14], td + 58 * 15, E5, O5);
      slot_taps(acc[15], td + 59 * 15, E5, O5);
    }
  }

  // ---- epilogue: A*tanh(S*y) and store ----
  const size_t out_img = (size_t)b * 16;
  #pragma unroll
  for (int k = 0; k < 16; ++k) {
    const size_t off = ((out_img + k) * OH + oy) * OW + ox;
    *(float2*)&out[off]     = make_float2(act(acc[k][0]), act(acc[k][1]));
    *(float2*)&out[off + 2] = make_float2(act(acc[k][2]), act(acc[k][3]));
  }
}

extern "C" void kernel_launch(void* const* d_in, const int* in_sizes, int n_in,
                              void* d_out, int out_size, void* d_ws, size_t ws_size,
                              hipStream_t stream) {
  const float* x  = (const float*)d_in[0];
  const float* w3 = (const float*)d_in[1];
  const float* b3 = (const float*)d_in[2];
  const float* w4 = (const float*)d_in[3];
  const float* b4 = (const float*)d_in[4];
  const float* w6 = (const float*)d_in[5];
  const float* b6 = (const float*)d_in[6];
  float* out = (float*)d_out;
  unsigned int* tab = (unsigned int*)d_ws;  // 900 dwords

  hipLaunchKernelGGL(wpack_kernel, dim3(4), dim3(256), 0, stream, w3, w4, w6, tab);

  dim3 grid(3, 9, 256);     // x-tiles, y-tiles, batch
  dim3 block(NTHREADS);
  hipLaunchKernelGGL(c3_kernel, grid, block, 0, stream, x, b3, b4, b6, tab, out);
}